// Round 3
// baseline (197.362 us; speedup 1.0000x reference)
//
#include <hip/hip_runtime.h>
#include <stdint.h>
#include <stddef.h>

typedef __attribute__((ext_vector_type(8))) short short8;
typedef __attribute__((ext_vector_type(4))) float f32x4;
typedef __attribute__((ext_vector_type(4))) short short4v;

__device__ __forceinline__ short f2bf(float f) {
  unsigned u = __builtin_bit_cast(unsigned, f);
  u = (u + 0x7fffu + ((u >> 16) & 1u)) >> 16;
  return (short)u;
}

__device__ __forceinline__ void gload16(const void* g, void* l) {
  __builtin_amdgcn_global_load_lds(
      (const __attribute__((address_space(1))) unsigned int*)g,
      (__attribute__((address_space(3))) unsigned int*)l, 16, 0, 0);
}

// ---------------- conversion kernels (merged) ----------------

__global__ __launch_bounds__(256)
void cvt_misc_k(const float* __restrict__ x, const float* __restrict__ nw1,
                const float* __restrict__ lb2, short* __restrict__ xb,
                short* __restrict__ BTn, short* __restrict__ BT2) {
  const int bx = blockIdx.x;
  if (bx < 3072) {
    const int i = bx * 256 + threadIdx.x;
    const float4 v = ((const float4*)x)[i];
    short4v o;
    o.x = f2bf(v.x); o.y = f2bf(v.y); o.z = f2bf(v.z); o.w = f2bf(v.w);
    *(short4v*)(xb + (size_t)i * 4) = o;
  } else if (bx < 6144) {
    const int idx = (bx - 3072) * 256 + threadIdx.x;  // 1024*768
    const int i = idx % 768;
    const int nh = idx / 768;
    float v = 0.f;
    if (nh < 1008) v = nw1[((size_t)(nh >> 4) * 768 + i) * 16 + (nh & 15)];
    BTn[idx] = f2bf(v);
  } else {
    const int idx = (bx - 6144) * 256 + threadIdx.x;  // 768*64
    const int o = idx >> 6, l = idx & 63;
    BT2[(size_t)o * 8256 + 8192 + l] = f2bf(lb2[(size_t)l * 768 + o]);
  }
}

__global__ __launch_bounds__(256)
void cvt_w_k(const float* __restrict__ lw1, const float* __restrict__ lw2,
             short* __restrict__ BT1, short* __restrict__ BT2) {
  __shared__ float tile[64][65];
  const int tid = threadIdx.x;
  if (blockIdx.z < 64) {
    const int l = blockIdx.z, h0 = blockIdx.y * 64, i0 = blockIdx.x * 64;
#pragma unroll
    for (int t = 0; t < 16; ++t) {
      const int e = t * 256 + tid;
      const int ii = e >> 6, hh = e & 63;
      tile[ii][hh] = lw1[(size_t)l * 98304 + (size_t)(i0 + ii) * 128 + (h0 + hh)];
    }
    __syncthreads();
#pragma unroll
    for (int t = 0; t < 16; ++t) {
      const int e = t * 256 + tid;
      const int hh = e >> 6, ii = e & 63;
      BT1[(size_t)(l * 128 + h0 + hh) * 768 + i0 + ii] = f2bf(tile[ii][hh]);
    }
  } else {
    const int l = blockIdx.z - 64, h0 = blockIdx.y * 64, o0 = blockIdx.x * 64;
#pragma unroll
    for (int t = 0; t < 16; ++t) {
      const int e = t * 256 + tid;
      const int hh = e >> 6, oo = e & 63;
      tile[hh][oo] = lw2[(size_t)l * 98304 + (size_t)(h0 + hh) * 768 + (o0 + oo)];
    }
    __syncthreads();
#pragma unroll
    for (int t = 0; t < 16; ++t) {
      const int e = t * 256 + tid;
      const int oo = e >> 6, hh = e & 63;
      BT2[(size_t)(o0 + oo) * 8256 + l * 128 + h0 + hh] = f2bf(tile[hh][oo]);
    }
  }
}

// ---------------- gate kernel ----------------
__global__ __launch_bounds__(256)
void gates_k(const float* __restrict__ hn, const float* __restrict__ nb1,
             const float* __restrict__ nw2, const float* __restrict__ nb2,
             float* __restrict__ wgt, short* __restrict__ hs) {
  const int b = blockIdx.x * 4 + (threadIdx.x >> 6);
  const int lane = threadIdx.x & 63;
  float c = 0.f;
  if (lane < 63) {
    float s = nb2[lane];
    const float* h = hn + (size_t)b * 1024 + lane * 16;
#pragma unroll
    for (int j = 0; j < 16; ++j) {
      float v = fmaxf(h[j] + nb1[lane * 16 + j], 0.f);
      s += v * nw2[lane * 16 + j];
    }
    c = 1.f / (1.f + expf(-s));
  }
  float w = 1.f;
#pragma unroll
  for (int lvl = 0; lvl < 6; ++lvl) {
    const int idx = (1 << lvl) - 1 + (lane >> (6 - lvl));
    const float g = __shfl(c, idx, 64);
    w *= ((lane >> (5 - lvl)) & 1) ? (1.f - g) : g;
  }
  wgt[(size_t)b * 64 + lane] = w;
  hs[(size_t)b * 8256 + 8192 + lane] = f2bf(w);
}

// ---------------- gemm3: deep-pipelined C = A(MxK) * B^T(NxK) ----------------
// Double-buffered K-tiles (BK=64), counted vmcnt(8) (never drains in-loop),
// raw s_barrier, setprio around MFMA. XOR-swizzled LDS via pre-swizzled global
// source (linear gload_lds dest). EPI0: f32 to {Cv,P1,P2}[z]. EPI1: bf16
// relu(acc+bias[col])*wgt[row][col>>7].
template <int BM, int BN, int WM, int WN, int EPI>
__global__ __launch_bounds__(WM * WN * 64, 2)
void gemm3(const short* __restrict__ A, const short* __restrict__ B,
           void* __restrict__ Cv, float* __restrict__ P1, float* __restrict__ P2,
           int KT, int ks, int lda, int ldb, int ldc, int nx, int ny, int xfirst,
           const float* __restrict__ bias, const float* __restrict__ wgt) {
  constexpr int THREADS = WM * WN * 64;
  constexpr int ABYTES = BM * 128;  // BM x 64 cols x 2B
  constexpr int BBYTES = BN * 128;
  constexpr int TILEB = ABYTES + BBYTES;
  constexpr int NLOAD = TILEB / (THREADS * 16);
  static_assert(NLOAD == 8, "vmcnt literal assumes 8 loads/tile/thread");
  constexpr int WMR = BM / WM, WNR = BN / WN;
  constexpr int FM = WMR / 16, FN = WNR / 16;
  __shared__ char lds[2 * TILEB];

  const int tid = threadIdx.x, lane = tid & 63, wid = tid >> 6;
  const int wm = wid / WN, wn = wid % WN;

  const int cpx = gridDim.x >> 3;  // grid % 8 == 0
  const int sid = (blockIdx.x & 7) * cpx + (blockIdx.x >> 3);
  int xg, yg, z;
  if (xfirst) { xg = sid % nx; const int t = sid / nx; yg = t % ny; z = t / ny; }
  else        { yg = sid % ny; const int t = sid / ny; xg = t % nx; z = t / nx; }
  const int m0 = yg * BM, n0 = xg * BN;
  const int kt0 = z * ks;
  const int ktn = min(ks, KT - kt0);

  f32x4 acc[FM][FN];
  const f32x4 zero = {0.f, 0.f, 0.f, 0.f};
#pragma unroll
  for (int i = 0; i < FM; ++i)
#pragma unroll
    for (int j = 0; j < FN; ++j) acc[i][j] = zero;

  auto stage = [&](int buf, int kt) {
    const int k0 = kt * 64;
    char* bufp = lds + buf * TILEB;
#pragma unroll
    for (int s = 0; s < NLOAD; ++s) {
      const int off = s * (THREADS * 16) + tid * 16;
      const short* src;
      if (off < ABYTES) {
        const int r = off >> 7;
        const int cs = ((off >> 4) & 7) ^ (r & 7);
        src = A + (size_t)(m0 + r) * lda + k0 + cs * 8;
      } else {
        const int o2 = off - ABYTES;
        const int r = o2 >> 7;
        const int cs = ((o2 >> 4) & 7) ^ (r & 7);
        src = B + (size_t)(n0 + r) * ldb + k0 + cs * 8;
      }
      gload16(src, bufp + off);
    }
  };

  stage(0, kt0);
  for (int ki = 0; ki < ktn; ++ki) {
    const int buf = ki & 1;
    __builtin_amdgcn_s_barrier();  // all waves done reading buf^1 (tile ki-1)
    if (ki + 1 < ktn) {
      stage(buf ^ 1, kt0 + ki + 1);
      // outstanding: tile ki (8, oldest) + tile ki+1 (8). Wait tile ki only.
      asm volatile("s_waitcnt vmcnt(8)" ::: "memory");
    } else {
      asm volatile("s_waitcnt vmcnt(0)" ::: "memory");
    }
    __builtin_amdgcn_s_barrier();  // tile ki resident in LDS for all waves

    const char* ldsA = lds + buf * TILEB;
    const char* ldsB = ldsA + ABYTES;
#pragma unroll
    for (int kk = 0; kk < 2; ++kk) {
      const int chunk = kk * 4 + (lane >> 4);
      short8 af[FM], bfr[FN];
#pragma unroll
      for (int i = 0; i < FM; ++i) {
        const int row = wm * WMR + i * 16 + (lane & 15);
        af[i] = *(const short8*)(ldsA + row * 128 + ((chunk ^ (row & 7)) << 4));
      }
#pragma unroll
      for (int j = 0; j < FN; ++j) {
        const int row = wn * WNR + j * 16 + (lane & 15);
        bfr[j] = *(const short8*)(ldsB + row * 128 + ((chunk ^ (row & 7)) << 4));
      }
      __builtin_amdgcn_s_setprio(1);
#pragma unroll
      for (int i = 0; i < FM; ++i)
#pragma unroll
        for (int j = 0; j < FN; ++j)
          acc[i][j] = __builtin_amdgcn_mfma_f32_16x16x32_bf16(af[i], bfr[j], acc[i][j], 0, 0, 0);
      __builtin_amdgcn_s_setprio(0);
    }
  }

  const int row_base = m0 + wm * WMR + (lane >> 4) * 4;
  const int col_base = n0 + wn * WNR + (lane & 15);
  if constexpr (EPI == 1) {
    short* C = (short*)Cv;
#pragma unroll
    for (int j = 0; j < FN; ++j) {
      const int col = col_base + j * 16;
      const int leaf = (n0 + wn * WNR + j * 16) >> 7;
      const float b = bias[col];
#pragma unroll
      for (int i = 0; i < FM; ++i)
#pragma unroll
        for (int r = 0; r < 4; ++r) {
          const int row = row_base + i * 16 + r;
          const float v = fmaxf(acc[i][j][r] + b, 0.f) * wgt[(size_t)row * 64 + leaf];
          C[(size_t)row * ldc + col] = f2bf(v);
        }
    }
  } else {
    float* C = (z == 0) ? (float*)Cv : (z == 1 ? P1 : P2);
#pragma unroll
    for (int i = 0; i < FM; ++i)
#pragma unroll
      for (int j = 0; j < FN; ++j) {
        const int col = col_base + j * 16;
#pragma unroll
        for (int r = 0; r < 4; ++r) {
          const int row = row_base + i * 16 + r;
          C[(size_t)row * ldc + col] = acc[i][j][r];
        }
      }
  }
}

// ---------------- split-K reduce: out += p1 + p2 ----------------
__global__ __launch_bounds__(256)
void reduce_k(float* __restrict__ out, const float* __restrict__ p1,
              const float* __restrict__ p2) {
  const int i = blockIdx.x * 256 + threadIdx.x;  // 786432 threads, f32x4 each
  f32x4 a = ((const f32x4*)out)[i];
  f32x4 b = ((const f32x4*)p1)[i];
  f32x4 c = ((const f32x4*)p2)[i];
  ((f32x4*)out)[i] = a + b + c;
}

// ---------------- launch ----------------

extern "C" void kernel_launch(void* const* d_in, const int* in_sizes, int n_in,
                              void* d_out, int out_size, void* d_ws, size_t ws_size,
                              hipStream_t stream) {
  const float* x   = (const float*)d_in[0];
  const float* nw1 = (const float*)d_in[1];
  const float* nb1 = (const float*)d_in[2];
  const float* nw2 = (const float*)d_in[3];
  const float* nb2 = (const float*)d_in[4];
  const float* lw1 = (const float*)d_in[5];
  const float* lb1 = (const float*)d_in[6];
  const float* lw2 = (const float*)d_in[7];
  const float* lb2 = (const float*)d_in[8];

  char* ws = (char*)d_ws;
  short* xb  = (short*)(ws + 0);         // 6,291,456   (dead after gemm1)
  short* BTn = (short*)(ws + 6291456);   // 1,572,864   (dead after node gemm)
  short* BT1 = (short*)(ws + 7864320);   // 12,582,912  (dead after gemm1)
  short* BT2 = (short*)(ws + 20447232);  // 12,681,216  (live in gemm2)
  float* hn  = (float*)(ws + 33128448);  // 16,777,216  (dead after gates)
  float* wgt = (float*)(ws + 49905664);  // 1,048,576   (dead after gemm1)
  short* hs  = (short*)(ws + 50954240);  // 67,633,152  (live in gemm2)
  float* p1  = (float*)(ws + 0);         // 12,582,912  (over xb+BTn+BT1 head)
  float* p2  = (float*)(ws + 33128448);  // 12,582,912  (over hn)

  // 1. conversions
  cvt_misc_k<<<6336, 256, 0, stream>>>(x, nw1, lb2, xb, BTn, BT2);
  cvt_w_k<<<dim3(12, 2, 128), 256, 0, stream>>>(lw1, lw2, BT1, BT2);

  // 2. node GEMM: hn = xb @ BTn^T (4096x1024, K=768)
  gemm3<128, 128, 2, 2, 0><<<256, 256, 0, stream>>>(
      xb, BTn, hn, nullptr, nullptr, 12, 12, 768, 768, 1024, 8, 32, 1,
      nullptr, nullptr);
  // 3. gates
  gates_k<<<1024, 256, 0, stream>>>(hn, nb1, nw2, nb2, wgt, hs);

  // 4. hs = bf16(relu(xb @ BT1^T + b1) * w[leaf])  (4096x8192, K=768), 256^2 tile
  gemm3<256, 256, 2, 4, 1><<<512, 512, 0, stream>>>(
      xb, BT1, hs, nullptr, nullptr, 12, 12, 768, 768, 8256, 32, 16, 0,
      lb1, wgt);

  // 5. out = hs @ BT2^T (4096x768, K=8256; b2 folded via K-ext), split-K=3
  gemm3<128, 128, 2, 2, 0><<<576, 256, 0, stream>>>(
      hs, BT2, (float*)d_out, p1, p2, 129, 43, 8256, 8256, 768, 6, 32, 1,
      nullptr, nullptr);
  // 6. out += p1 + p2
  reduce_k<<<3072, 256, 0, stream>>>((float*)d_out, p1, p2);
}

// Round 4
// 191.741 us; speedup vs baseline: 1.0293x; 1.0293x over previous
//
#include <hip/hip_runtime.h>
#include <stdint.h>
#include <stddef.h>

typedef __attribute__((ext_vector_type(8))) short short8;
typedef __attribute__((ext_vector_type(4))) float f32x4;
typedef __attribute__((ext_vector_type(4))) short short4v;

__device__ __forceinline__ short f2bf(float f) {
  unsigned u = __builtin_bit_cast(unsigned, f);
  u = (u + 0x7fffu + ((u >> 16) & 1u)) >> 16;
  return (short)u;
}

__device__ __forceinline__ void gload16(const void* g, void* l) {
  __builtin_amdgcn_global_load_lds(
      (const __attribute__((address_space(1))) unsigned int*)g,
      (__attribute__((address_space(3))) unsigned int*)l, 16, 0, 0);
}

// ---------------- conversion kernels (merged) ----------------

__global__ __launch_bounds__(256)
void cvt_misc_k(const float* __restrict__ x, const float* __restrict__ nw1,
                const float* __restrict__ lb2, short* __restrict__ xb,
                short* __restrict__ BTn, short* __restrict__ BT2) {
  const int bx = blockIdx.x;
  if (bx < 3072) {
    const int i = bx * 256 + threadIdx.x;
    const float4 v = ((const float4*)x)[i];
    short4v o;
    o.x = f2bf(v.x); o.y = f2bf(v.y); o.z = f2bf(v.z); o.w = f2bf(v.w);
    *(short4v*)(xb + (size_t)i * 4) = o;
  } else if (bx < 6144) {
    const int idx = (bx - 3072) * 256 + threadIdx.x;  // 1024*768
    const int i = idx % 768;
    const int nh = idx / 768;
    float v = 0.f;
    if (nh < 1008) v = nw1[((size_t)(nh >> 4) * 768 + i) * 16 + (nh & 15)];
    BTn[idx] = f2bf(v);
  } else {
    const int idx = (bx - 6144) * 256 + threadIdx.x;  // 768*64
    const int o = idx >> 6, l = idx & 63;
    BT2[(size_t)o * 8256 + 8192 + l] = f2bf(lb2[(size_t)l * 768 + o]);
  }
}

__global__ __launch_bounds__(256)
void cvt_w_k(const float* __restrict__ lw1, const float* __restrict__ lw2,
             short* __restrict__ BT1, short* __restrict__ BT2) {
  __shared__ float tile[64][65];
  const int tid = threadIdx.x;
  if (blockIdx.z < 64) {
    const int l = blockIdx.z, h0 = blockIdx.y * 64, i0 = blockIdx.x * 64;
#pragma unroll
    for (int t = 0; t < 16; ++t) {
      const int e = t * 256 + tid;
      const int ii = e >> 6, hh = e & 63;
      tile[ii][hh] = lw1[(size_t)l * 98304 + (size_t)(i0 + ii) * 128 + (h0 + hh)];
    }
    __syncthreads();
#pragma unroll
    for (int t = 0; t < 16; ++t) {
      const int e = t * 256 + tid;
      const int hh = e >> 6, ii = e & 63;
      BT1[(size_t)(l * 128 + h0 + hh) * 768 + i0 + ii] = f2bf(tile[ii][hh]);
    }
  } else {
    const int l = blockIdx.z - 64, h0 = blockIdx.y * 64, o0 = blockIdx.x * 64;
#pragma unroll
    for (int t = 0; t < 16; ++t) {
      const int e = t * 256 + tid;
      const int hh = e >> 6, oo = e & 63;
      tile[hh][oo] = lw2[(size_t)l * 98304 + (size_t)(h0 + hh) * 768 + (o0 + oo)];
    }
    __syncthreads();
#pragma unroll
    for (int t = 0; t < 16; ++t) {
      const int e = t * 256 + tid;
      const int oo = e >> 6, hh = e & 63;
      BT2[(size_t)(o0 + oo) * 8256 + l * 128 + h0 + hh] = f2bf(tile[hh][oo]);
    }
  }
}

// ---------------- gate kernel ----------------
__global__ __launch_bounds__(256)
void gates_k(const float* __restrict__ hn, const float* __restrict__ nb1,
             const float* __restrict__ nw2, const float* __restrict__ nb2,
             float* __restrict__ wgt, short* __restrict__ hs) {
  const int b = blockIdx.x * 4 + (threadIdx.x >> 6);
  const int lane = threadIdx.x & 63;
  float c = 0.f;
  if (lane < 63) {
    float s = nb2[lane];
    const float* h = hn + (size_t)b * 1024 + lane * 16;
#pragma unroll
    for (int j = 0; j < 16; ++j) {
      float v = fmaxf(h[j] + nb1[lane * 16 + j], 0.f);
      s += v * nw2[lane * 16 + j];
    }
    c = 1.f / (1.f + expf(-s));
  }
  float w = 1.f;
#pragma unroll
  for (int lvl = 0; lvl < 6; ++lvl) {
    const int idx = (1 << lvl) - 1 + (lane >> (6 - lvl));
    const float g = __shfl(c, idx, 64);
    w *= ((lane >> (5 - lvl)) & 1) ? (1.f - g) : g;
  }
  wgt[(size_t)b * 64 + lane] = w;
  hs[(size_t)b * 8256 + 8192 + lane] = f2bf(w);
}

// ---------------- gemm4: m97-structure C = A(MxK) * B^T(NxK) ----------------
// Single-buffered LDS (32/24 KB), 2 barriers/K-tile, 4 waves, MAXB blocks/CU
// for implicit cross-block overlap (m114). Source-side XOR swizzle (0 bank
// conflicts). EPI0: f32 to {Cv,P1,P2}[z]. EPI1: bf16 relu(acc+bias)*wgt.
template <int BM, int EPI, int MAXB>
__global__ __launch_bounds__(256, MAXB)
void gemm4(const short* __restrict__ A, const short* __restrict__ B,
           void* __restrict__ Cv, float* __restrict__ P1, float* __restrict__ P2,
           int KT, int ks, int lda, int ldb, int ldc, int nx, int ny, int xfirst,
           const float* __restrict__ bias, const float* __restrict__ wgt) {
  constexpr int ABYTES = BM * 128;   // BM rows x 64 k x 2B
  constexpr int BBYTES = 128 * 128;  // BN=128
  constexpr int FM = BM / 32;
  constexpr int NLOAD = (ABYTES + BBYTES) / (256 * 16);
  __shared__ char lds[ABYTES + BBYTES];

  const int tid = threadIdx.x, lane = tid & 63, wid = tid >> 6;
  const int wm = wid >> 1, wn = wid & 1;

  const int cpx = gridDim.x >> 3;  // grid % 8 == 0
  const int sid = (blockIdx.x & 7) * cpx + (blockIdx.x >> 3);
  int xg, yg, z;
  if (xfirst) { xg = sid % nx; const int t = sid / nx; yg = t % ny; z = t / ny; }
  else        { yg = sid % ny; const int t = sid / ny; xg = t % nx; z = t / nx; }
  const int m0 = yg * BM, n0 = xg * 128;
  const int kt0 = z * ks;
  const int ktn = min(ks, KT - kt0);

  f32x4 acc[FM][4];
  const f32x4 zero = {0.f, 0.f, 0.f, 0.f};
#pragma unroll
  for (int i = 0; i < FM; ++i)
#pragma unroll
    for (int j = 0; j < 4; ++j) acc[i][j] = zero;

  for (int ki = 0; ki < ktn; ++ki) {
    const int k0 = (kt0 + ki) * 64;
    __syncthreads();  // all waves done reading previous tile
#pragma unroll
    for (int s = 0; s < NLOAD; ++s) {
      const int off = s * 4096 + tid * 16;
      const short* src;
      if (off < ABYTES) {
        const int r = off >> 7;
        const int cs = ((off >> 4) & 7) ^ (r & 7);  // inverse-swizzled source
        src = A + (size_t)(m0 + r) * lda + k0 + cs * 8;
      } else {
        const int o2 = off - ABYTES;
        const int r = o2 >> 7;
        const int cs = ((o2 >> 4) & 7) ^ (r & 7);
        src = B + (size_t)(n0 + r) * ldb + k0 + cs * 8;
      }
      gload16(src, lds + off);
    }
    __syncthreads();  // compiler drains vmcnt before barrier: tile resident

    const char* ldsA = lds;
    const char* ldsB = lds + ABYTES;
#pragma unroll
    for (int kk = 0; kk < 2; ++kk) {
      const int chunk = kk * 4 + (lane >> 4);
      short8 af[FM], bfr[4];
#pragma unroll
      for (int i = 0; i < FM; ++i) {
        const int row = wm * (BM / 2) + i * 16 + (lane & 15);
        af[i] = *(const short8*)(ldsA + row * 128 + ((chunk ^ (row & 7)) << 4));
      }
#pragma unroll
      for (int j = 0; j < 4; ++j) {
        const int row = wn * 64 + j * 16 + (lane & 15);
        bfr[j] = *(const short8*)(ldsB + row * 128 + ((chunk ^ (row & 7)) << 4));
      }
      __builtin_amdgcn_s_setprio(1);
#pragma unroll
      for (int i = 0; i < FM; ++i)
#pragma unroll
        for (int j = 0; j < 4; ++j)
          acc[i][j] = __builtin_amdgcn_mfma_f32_16x16x32_bf16(af[i], bfr[j], acc[i][j], 0, 0, 0);
      __builtin_amdgcn_s_setprio(0);
    }
  }

  const int row_base = m0 + wm * (BM / 2) + (lane >> 4) * 4;
  const int col_base = n0 + wn * 64 + (lane & 15);
  if constexpr (EPI == 1) {
    short* C = (short*)Cv;
    const int leaf = n0 >> 7;
#pragma unroll
    for (int i = 0; i < FM; ++i)
#pragma unroll
      for (int j = 0; j < 4; ++j) {
        const int col = col_base + j * 16;
        const float b = bias[col];
#pragma unroll
        for (int r = 0; r < 4; ++r) {
          const int row = row_base + i * 16 + r;
          const float v = fmaxf(acc[i][j][r] + b, 0.f) * wgt[(size_t)row * 64 + leaf];
          C[(size_t)row * ldc + col] = f2bf(v);
        }
      }
  } else {
    float* C = (z == 0) ? (float*)Cv : (z == 1 ? P1 : P2);
#pragma unroll
    for (int i = 0; i < FM; ++i)
#pragma unroll
      for (int j = 0; j < 4; ++j) {
        const int col = col_base + j * 16;
#pragma unroll
        for (int r = 0; r < 4; ++r) {
          const int row = row_base + i * 16 + r;
          C[(size_t)row * ldc + col] = acc[i][j][r];
        }
      }
  }
}

// ---------------- split-K reduce: out += p1 + p2 ----------------
__global__ __launch_bounds__(256)
void reduce_k(float* __restrict__ out, const float* __restrict__ p1,
              const float* __restrict__ p2) {
  const int i = blockIdx.x * 256 + threadIdx.x;  // 786432 threads, f32x4 each
  f32x4 a = ((const f32x4*)out)[i];
  f32x4 b = ((const f32x4*)p1)[i];
  f32x4 c = ((const f32x4*)p2)[i];
  ((f32x4*)out)[i] = a + b + c;
}

// ---------------- launch ----------------

extern "C" void kernel_launch(void* const* d_in, const int* in_sizes, int n_in,
                              void* d_out, int out_size, void* d_ws, size_t ws_size,
                              hipStream_t stream) {
  const float* x   = (const float*)d_in[0];
  const float* nw1 = (const float*)d_in[1];
  const float* nb1 = (const float*)d_in[2];
  const float* nw2 = (const float*)d_in[3];
  const float* nb2 = (const float*)d_in[4];
  const float* lw1 = (const float*)d_in[5];
  const float* lb1 = (const float*)d_in[6];
  const float* lw2 = (const float*)d_in[7];
  const float* lb2 = (const float*)d_in[8];

  char* ws = (char*)d_ws;
  short* xb  = (short*)(ws + 0);         // 6,291,456   (dead after gemm1)
  short* BTn = (short*)(ws + 6291456);   // 1,572,864   (dead after node gemm)
  short* BT1 = (short*)(ws + 7864320);   // 12,582,912  (dead after gemm1)
  short* BT2 = (short*)(ws + 20447232);  // 12,681,216  (live in gemm2)
  float* hn  = (float*)(ws + 33128448);  // 16,777,216  (dead after gates)
  float* wgt = (float*)(ws + 49905664);  // 1,048,576   (dead after gemm1)
  short* hs  = (short*)(ws + 50954240);  // 67,633,152  (live in gemm2)
  float* p1  = (float*)(ws + 0);         // 12,582,912  (over xb+BTn+BT1 head)
  float* p2  = (float*)(ws + 33128448);  // 12,582,912  (over hn)

  // 1. conversions
  cvt_misc_k<<<6336, 256, 0, stream>>>(x, nw1, lb2, xb, BTn, BT2);
  cvt_w_k<<<dim3(12, 2, 128), 256, 0, stream>>>(lw1, lw2, BT1, BT2);

  // 2. node GEMM: hn = xb @ BTn^T (4096x1024, K=768)
  gemm4<128, 0, 3><<<256, 256, 0, stream>>>(
      xb, BTn, hn, nullptr, nullptr, 12, 12, 768, 768, 1024, 8, 32, 1,
      nullptr, nullptr);
  // 3. gates
  gates_k<<<1024, 256, 0, stream>>>(hn, nb1, nw2, nb2, wgt, hs);

  // 4. hs = bf16(relu(xb @ BT1^T + b1) * w[leaf])  (4096x8192, K=768)
  gemm4<128, 1, 3><<<2048, 256, 0, stream>>>(
      xb, BT1, hs, nullptr, nullptr, 12, 12, 768, 768, 8256, 64, 32, 0,
      lb1, wgt);

  // 5. out = hs @ BT2^T (4096x768, K=8256; b2 folded via K-ext), split-K=3
  gemm4<64, 0, 4><<<1152, 256, 0, stream>>>(
      hs, BT2, (float*)d_out, p1, p2, 129, 43, 8256, 8256, 768, 6, 64, 1,
      nullptr, nullptr);
  // 6. out += p1 + p2
  reduce_k<<<3072, 256, 0, stream>>>((float*)d_out, p1, p2);
}

// Round 5
// 181.113 us; speedup vs baseline: 1.0897x; 1.0587x over previous
//
#include <hip/hip_runtime.h>
#include <stdint.h>
#include <stddef.h>

typedef __attribute__((ext_vector_type(8))) short short8;
typedef __attribute__((ext_vector_type(4))) float f32x4;
typedef __attribute__((ext_vector_type(4))) short short4v;

__device__ __forceinline__ short f2bf(float f) {
  unsigned u = __builtin_bit_cast(unsigned, f);
  u = (u + 0x7fffu + ((u >> 16) & 1u)) >> 16;
  return (short)u;
}

__device__ __forceinline__ void gload16(const void* g, void* l) {
  __builtin_amdgcn_global_load_lds(
      (const __attribute__((address_space(1))) unsigned int*)g,
      (__attribute__((address_space(3))) unsigned int*)l, 16, 0, 0);
}

// ---------------- conversion kernels ----------------

__global__ __launch_bounds__(256)
void cvt_misc_k(const float* __restrict__ x, const float* __restrict__ nw1,
                const float* __restrict__ lb2, short* __restrict__ xb,
                short* __restrict__ BTn, short* __restrict__ BT2) {
  const int bx = blockIdx.x;
  if (bx < 3072) {
    const int i = bx * 256 + threadIdx.x;
    const float4 v = ((const float4*)x)[i];
    short4v o;
    o.x = f2bf(v.x); o.y = f2bf(v.y); o.z = f2bf(v.z); o.w = f2bf(v.w);
    *(short4v*)(xb + (size_t)i * 4) = o;
  } else if (bx < 6144) {
    const int idx = (bx - 3072) * 256 + threadIdx.x;  // 1024*768
    const int i = idx % 768;
    const int nh = idx / 768;
    float v = 0.f;
    if (nh < 1008) v = nw1[((size_t)(nh >> 4) * 768 + i) * 16 + (nh & 15)];
    BTn[idx] = f2bf(v);
  } else {
    const int idx = (bx - 6144) * 256 + threadIdx.x;  // 768*64
    const int o = idx >> 6, l = idx & 63;
    BT2[(size_t)o * 8256 + 8192 + l] = f2bf(lb2[(size_t)l * 768 + o]);
  }
}

// Fused: blocks [0,512) = node GEMM hn = xb @ BTn^T (4096x1024, K=768, BM=64);
// blocks [512, 3584) = weight transposes (lw1->BT1, lw2->BT2). Independent work
// sharing one launch so the node GEMM hides under the conversions.
__global__ __launch_bounds__(256, 4)
void node_cvt_k(const short* __restrict__ xb, const short* __restrict__ BTn,
                float* __restrict__ hn, const float* __restrict__ lw1,
                const float* __restrict__ lw2, short* __restrict__ BT1,
                short* __restrict__ BT2) {
  __shared__ char sh[24576];
  const int tid = threadIdx.x;
  if (blockIdx.x < 512) {
    // ---- node GEMM, gemm4 structure, BM=64 BN=128 BK=64 ----
    constexpr int ABYTES = 64 * 128, BBYTES = 128 * 128;
    const int lane = tid & 63, wid = tid >> 6;
    const int wm = wid >> 1, wn = wid & 1;
    const int sid = (blockIdx.x & 7) * 64 + (blockIdx.x >> 3);
    const int xg = sid % 8, yg = sid / 8;
    const int m0 = yg * 64, n0 = xg * 128;
    f32x4 acc[2][4];
    const f32x4 zero = {0.f, 0.f, 0.f, 0.f};
#pragma unroll
    for (int i = 0; i < 2; ++i)
#pragma unroll
      for (int j = 0; j < 4; ++j) acc[i][j] = zero;
    for (int ki = 0; ki < 12; ++ki) {
      const int k0 = ki * 64;
      __syncthreads();
#pragma unroll
      for (int s = 0; s < 6; ++s) {
        const int off = s * 4096 + tid * 16;
        const short* src;
        if (off < ABYTES) {
          const int r = off >> 7;
          const int cs = ((off >> 4) & 7) ^ (r & 7);
          src = xb + (size_t)(m0 + r) * 768 + k0 + cs * 8;
        } else {
          const int o2 = off - ABYTES;
          const int r = o2 >> 7;
          const int cs = ((o2 >> 4) & 7) ^ (r & 7);
          src = BTn + (size_t)(n0 + r) * 768 + k0 + cs * 8;
        }
        gload16(src, sh + off);
      }
      __syncthreads();
#pragma unroll
      for (int kk = 0; kk < 2; ++kk) {
        const int chunk = kk * 4 + (lane >> 4);
        short8 af[2], bfr[4];
#pragma unroll
        for (int i = 0; i < 2; ++i) {
          const int row = wm * 32 + i * 16 + (lane & 15);
          af[i] = *(const short8*)(sh + row * 128 + ((chunk ^ (row & 7)) << 4));
        }
#pragma unroll
        for (int j = 0; j < 4; ++j) {
          const int row = wn * 64 + j * 16 + (lane & 15);
          bfr[j] = *(const short8*)(sh + ABYTES + row * 128 + ((chunk ^ (row & 7)) << 4));
        }
#pragma unroll
        for (int i = 0; i < 2; ++i)
#pragma unroll
          for (int j = 0; j < 4; ++j)
            acc[i][j] = __builtin_amdgcn_mfma_f32_16x16x32_bf16(af[i], bfr[j], acc[i][j], 0, 0, 0);
      }
    }
    const int row_base = m0 + wm * 32 + (lane >> 4) * 4;
    const int col_base = n0 + wn * 64 + (lane & 15);
#pragma unroll
    for (int i = 0; i < 2; ++i)
#pragma unroll
      for (int j = 0; j < 4; ++j)
#pragma unroll
        for (int r = 0; r < 4; ++r)
          hn[(size_t)(row_base + i * 16 + r) * 1024 + col_base + j * 16] = acc[i][j][r];
  } else {
    // ---- weight transpose ----
    float (*tile)[65] = (float(*)[65])sh;
    const int cb = blockIdx.x - 512;  // [0,3072)
    const int z = cb / 24, rem = cb % 24;
    const int by = rem / 12, bxx = rem % 12;
    const int h0 = by * 64, i0 = bxx * 64;
    if (z < 64) {
      const int l = z;
#pragma unroll
      for (int t = 0; t < 16; ++t) {
        const int e = t * 256 + tid;
        const int ii = e >> 6, hh = e & 63;
        tile[ii][hh] = lw1[(size_t)l * 98304 + (size_t)(i0 + ii) * 128 + (h0 + hh)];
      }
      __syncthreads();
#pragma unroll
      for (int t = 0; t < 16; ++t) {
        const int e = t * 256 + tid;
        const int hh = e >> 6, ii = e & 63;
        BT1[(size_t)(l * 128 + h0 + hh) * 768 + i0 + ii] = f2bf(tile[ii][hh]);
      }
    } else {
      const int l = z - 64;
      const int o0 = i0;
#pragma unroll
      for (int t = 0; t < 16; ++t) {
        const int e = t * 256 + tid;
        const int hh = e >> 6, oo = e & 63;
        tile[hh][oo] = lw2[(size_t)l * 98304 + (size_t)(h0 + hh) * 768 + (o0 + oo)];
      }
      __syncthreads();
#pragma unroll
      for (int t = 0; t < 16; ++t) {
        const int e = t * 256 + tid;
        const int oo = e >> 6, hh = e & 63;
        BT2[(size_t)(o0 + oo) * 8256 + l * 128 + h0 + hh] = f2bf(tile[hh][oo]);
      }
    }
  }
}

// ---------------- gate kernel ----------------
__global__ __launch_bounds__(256)
void gates_k(const float* __restrict__ hn, const float* __restrict__ nb1,
             const float* __restrict__ nw2, const float* __restrict__ nb2,
             float* __restrict__ wgt, short* __restrict__ hs) {
  const int b = blockIdx.x * 4 + (threadIdx.x >> 6);
  const int lane = threadIdx.x & 63;
  float c = 0.f;
  if (lane < 63) {
    float s = nb2[lane];
    const float* h = hn + (size_t)b * 1024 + lane * 16;
#pragma unroll
    for (int j = 0; j < 16; ++j) {
      float v = fmaxf(h[j] + nb1[lane * 16 + j], 0.f);
      s += v * nw2[lane * 16 + j];
    }
    c = 1.f / (1.f + expf(-s));
  }
  float w = 1.f;
#pragma unroll
  for (int lvl = 0; lvl < 6; ++lvl) {
    const int idx = (1 << lvl) - 1 + (lane >> (6 - lvl));
    const float g = __shfl(c, idx, 64);
    w *= ((lane >> (5 - lvl)) & 1) ? (1.f - g) : g;
  }
  wgt[(size_t)b * 64 + lane] = w;
  hs[(size_t)b * 8256 + 8192 + lane] = f2bf(w);
}

// ---------------- gemm8p: 256x256 8-phase GEMM1 ----------------
// C = bf16(relu(A @ B^T + bias) * wgt). 8 waves (2Mx4N), wave tile 128x64.
// LDS 128 KiB = 2 buf x (A 256x64 + B 256x64) bf16. BK=64, KT even.
// Stage ledger (iter k processes tiles 2k->b0, 2k+1->b1; halves 16KB, 2 loads):
//  ph1: A0(2k+1)->b1 | ph2: A1(2k+1)->b1, B0(2k+2)->b0 | ph3: B1(2k+2)->b0
//  ph4: -            | ph5: A0(2k+2)->b0 | ph6: A1(2k+2)->b0
//  ph7: B0(2k+3)->b1 | ph8: B1(2k+3)->b1
// Every stage targets a region whose last ds_read was >=1 barrier earlier.
// vmcnt(4) before the ph4/ph8 barrier covers the next half-iter's tile.
__global__ __launch_bounds__(512, 2)
void gemm8p(const short* __restrict__ A, const short* __restrict__ B,
            short* __restrict__ C, int KT, int lda, int ldb, int ldc,
            int nx, const float* __restrict__ bias, const float* __restrict__ wgt) {
  constexpr int ABYTES = 256 * 128;      // 32 KiB per matrix per buffer
  constexpr int TILEB = 2 * ABYTES;      // 64 KiB per buffer
  __shared__ char lds[2 * TILEB];        // 128 KiB

  const int tid = threadIdx.x, lane = tid & 63, wid = tid >> 6;
  const int wm = wid >> 2, wn = wid & 3;

  const int cpx = gridDim.x >> 3;
  const int sid = (blockIdx.x & 7) * cpx + (blockIdx.x >> 3);
  const int xg = sid % nx, yg = sid / nx;
  const int m0 = yg * 256, n0 = xg * 256;

  f32x4 acc[8][4];
  const f32x4 zero = {0.f, 0.f, 0.f, 0.f};
#pragma unroll
  for (int i = 0; i < 8; ++i)
#pragma unroll
    for (int j = 0; j < 4; ++j) acc[i][j] = zero;

  // stage one half-tile: mat 0=A,1=B; half h (128 rows); K-tile kt; buffer buf
  auto STG = [&](int buf, int mat, int h, int kt) {
    const int k0 = kt * 64;
    char* dst = lds + buf * TILEB + mat * ABYTES + h * 16384;
    const short* base = mat ? B : A;
    const int ld = mat ? ldb : lda;
    const int r0 = (mat ? n0 : m0) + h * 128;
#pragma unroll
    for (int s = 0; s < 2; ++s) {
      const int off = s * 8192 + tid * 16;
      const int r = off >> 7;                       // 0..127 within half
      const int cs = ((off >> 4) & 7) ^ (r & 7);    // inverse-swizzled source
      gload16(base + (size_t)(r0 + r) * ld + k0 + cs * 8, dst + off);
    }
  };

  short8 bfrag[4][2];
  auto RD_B = [&](int buf) {
    const char* bB = lds + buf * TILEB + ABYTES;
#pragma unroll
    for (int j = 0; j < 4; ++j)
#pragma unroll
      for (int kk = 0; kk < 2; ++kk) {
        const int row = wn * 64 + j * 16 + (lane & 15);
        const int chunk = kk * 4 + (lane >> 4);
        bfrag[j][kk] = *(const short8*)(bB + row * 128 + ((chunk ^ (row & 7)) << 4));
      }
  };

  // one phase: [rdB?] ; ds_read A quad q ; stages ; [vmcnt] ; barrier ; MFMA ; barrier
  auto PH = [&](int buf, int q, bool rdB, int vm, auto&& stages) {
    if (rdB) RD_B(buf);
    const char* bA = lds + buf * TILEB;
    short8 af[2][2];
#pragma unroll
    for (int i = 0; i < 2; ++i)
#pragma unroll
      for (int kk = 0; kk < 2; ++kk) {
        const int row = wm * 128 + q * 32 + i * 16 + (lane & 15);
        const int chunk = kk * 4 + (lane >> 4);
        af[i][kk] = *(const short8*)(bA + row * 128 + ((chunk ^ (row & 7)) << 4));
      }
    stages();
    if (vm == 4) asm volatile("s_waitcnt vmcnt(4)" ::: "memory");
    else if (vm == 0) asm volatile("s_waitcnt vmcnt(0)" ::: "memory");
    __builtin_amdgcn_s_barrier();
    __builtin_amdgcn_s_setprio(1);
#pragma unroll
    for (int kk = 0; kk < 2; ++kk)
#pragma unroll
      for (int i = 0; i < 2; ++i)
#pragma unroll
        for (int j = 0; j < 4; ++j)
          acc[q * 2 + i][j] =
              __builtin_amdgcn_mfma_f32_16x16x32_bf16(af[i][kk], bfrag[j][kk], acc[q * 2 + i][j], 0, 0, 0);
    __builtin_amdgcn_s_setprio(0);
    __builtin_amdgcn_s_barrier();
  };

  // prologue: tile0 (8 loads) + B(1) (4 loads); wait tile0; barrier
  STG(0, 0, 0, 0); STG(0, 0, 1, 0); STG(0, 1, 0, 0); STG(0, 1, 1, 0);
  STG(1, 1, 0, 1); STG(1, 1, 1, 1);
  asm volatile("s_waitcnt vmcnt(4)" ::: "memory");
  __builtin_amdgcn_s_barrier();

  const int iters = KT >> 1;
  for (int it = 0; it < iters; ++it) {
    const int t0 = it * 2;
    const bool last = (it == iters - 1);
    PH(0, 0, true, -1, [&] { if (t0 + 1 < KT) STG(1, 0, 0, t0 + 1); });
    PH(0, 1, false, -1, [&] {
      if (t0 + 1 < KT) STG(1, 0, 1, t0 + 1);
      if (t0 + 2 < KT) STG(0, 1, 0, t0 + 2);
    });
    PH(0, 2, false, -1, [&] { if (t0 + 2 < KT) STG(0, 1, 1, t0 + 2); });
    PH(0, 3, false, last ? 0 : 4, [] {});
    PH(1, 0, true, -1, [&] { if (t0 + 2 < KT) STG(0, 0, 0, t0 + 2); });
    PH(1, 1, false, -1, [&] { if (t0 + 2 < KT) STG(0, 0, 1, t0 + 2); });
    PH(1, 2, false, -1, [&] { if (t0 + 3 < KT) STG(1, 1, 0, t0 + 3); });
    PH(1, 3, false, last ? -1 : 4, [&] { if (t0 + 3 < KT) STG(1, 1, 1, t0 + 3); });
  }

  // epilogue: bf16( relu(acc + bias[col]) * wgt[row][leaf] )
#pragma unroll
  for (int mi = 0; mi < 8; ++mi) {
    const int row_base = m0 + wm * 128 + mi * 16 + (lane >> 4) * 4;
#pragma unroll
    for (int j = 0; j < 4; ++j) {
      const int col = n0 + wn * 64 + j * 16 + (lane & 15);
      const int leaf = col >> 7;
      const float b = bias[col];
#pragma unroll
      for (int r = 0; r < 4; ++r) {
        const int row = row_base + r;
        const float v = fmaxf(acc[mi][j][r] + b, 0.f) * wgt[(size_t)row * 64 + leaf];
        C[(size_t)row * ldc + col] = f2bf(v);
      }
    }
  }
}

// ---------------- gemm4 (m97 structure) for GEMM2 ----------------
template <int BM, int MAXB>
__global__ __launch_bounds__(256, MAXB)
void gemm4(const short* __restrict__ A, const short* __restrict__ B,
           float* __restrict__ Cv, float* __restrict__ P1, float* __restrict__ P2,
           int KT, int ks, int lda, int ldb, int ldc, int nx, int ny) {
  constexpr int ABYTES = BM * 128;
  constexpr int BBYTES = 128 * 128;
  constexpr int FM = BM / 32;
  constexpr int NLOAD = (ABYTES + BBYTES) / (256 * 16);
  __shared__ char lds[ABYTES + BBYTES];

  const int tid = threadIdx.x, lane = tid & 63, wid = tid >> 6;
  const int wm = wid >> 1, wn = wid & 1;

  const int cpx = gridDim.x >> 3;
  const int sid = (blockIdx.x & 7) * cpx + (blockIdx.x >> 3);
  const int xg = sid % nx;
  const int t1 = sid / nx;
  const int yg = t1 % ny;
  const int z = t1 / ny;
  const int m0 = yg * BM, n0 = xg * 128;
  const int kt0 = z * ks;
  const int ktn = min(ks, KT - kt0);

  f32x4 acc[FM][4];
  const f32x4 zero = {0.f, 0.f, 0.f, 0.f};
#pragma unroll
  for (int i = 0; i < FM; ++i)
#pragma unroll
    for (int j = 0; j < 4; ++j) acc[i][j] = zero;

  for (int ki = 0; ki < ktn; ++ki) {
    const int k0 = (kt0 + ki) * 64;
    __syncthreads();
#pragma unroll
    for (int s = 0; s < NLOAD; ++s) {
      const int off = s * 4096 + tid * 16;
      const short* src;
      if (off < ABYTES) {
        const int r = off >> 7;
        const int cs = ((off >> 4) & 7) ^ (r & 7);
        src = A + (size_t)(m0 + r) * lda + k0 + cs * 8;
      } else {
        const int o2 = off - ABYTES;
        const int r = o2 >> 7;
        const int cs = ((o2 >> 4) & 7) ^ (r & 7);
        src = B + (size_t)(n0 + r) * ldb + k0 + cs * 8;
      }
      gload16(src, lds + off);
    }
    __syncthreads();

    const char* ldsA = lds;
    const char* ldsB = lds + ABYTES;
#pragma unroll
    for (int kk = 0; kk < 2; ++kk) {
      const int chunk = kk * 4 + (lane >> 4);
      short8 af[FM], bfr[4];
#pragma unroll
      for (int i = 0; i < FM; ++i) {
        const int row = wm * (BM / 2) + i * 16 + (lane & 15);
        af[i] = *(const short8*)(ldsA + row * 128 + ((chunk ^ (row & 7)) << 4));
      }
#pragma unroll
      for (int j = 0; j < 4; ++j) {
        const int row = wn * 64 + j * 16 + (lane & 15);
        bfr[j] = *(const short8*)(ldsB + row * 128 + ((chunk ^ (row & 7)) << 4));
      }
      __builtin_amdgcn_s_setprio(1);
#pragma unroll
      for (int i = 0; i < FM; ++i)
#pragma unroll
        for (int j = 0; j < 4; ++j)
          acc[i][j] = __builtin_amdgcn_mfma_f32_16x16x32_bf16(af[i], bfr[j], acc[i][j], 0, 0, 0);
      __builtin_amdgcn_s_setprio(0);
    }
  }

  const int row_base = m0 + wm * (BM / 2) + (lane >> 4) * 4;
  const int col_base = n0 + wn * 64 + (lane & 15);
  float* C = (z == 0) ? Cv : (z == 1 ? P1 : P2);
#pragma unroll
  for (int i = 0; i < FM; ++i)
#pragma unroll
    for (int j = 0; j < 4; ++j) {
      const int col = col_base + j * 16;
#pragma unroll
      for (int r = 0; r < 4; ++r) {
        const int row = row_base + i * 16 + r;
        C[(size_t)row * ldc + col] = acc[i][j][r];
      }
    }
}

// ---------------- split-K reduce ----------------
__global__ __launch_bounds__(256)
void reduce_k(float* __restrict__ out, const float* __restrict__ p1,
              const float* __restrict__ p2) {
  const int i = blockIdx.x * 256 + threadIdx.x;
  f32x4 a = ((const f32x4*)out)[i];
  f32x4 b = ((const f32x4*)p1)[i];
  f32x4 c = ((const f32x4*)p2)[i];
  ((f32x4*)out)[i] = a + b + c;
}

// ---------------- launch ----------------

extern "C" void kernel_launch(void* const* d_in, const int* in_sizes, int n_in,
                              void* d_out, int out_size, void* d_ws, size_t ws_size,
                              hipStream_t stream) {
  const float* x   = (const float*)d_in[0];
  const float* nw1 = (const float*)d_in[1];
  const float* nb1 = (const float*)d_in[2];
  const float* nw2 = (const float*)d_in[3];
  const float* nb2 = (const float*)d_in[4];
  const float* lw1 = (const float*)d_in[5];
  const float* lb1 = (const float*)d_in[6];
  const float* lw2 = (const float*)d_in[7];
  const float* lb2 = (const float*)d_in[8];

  char* ws = (char*)d_ws;
  short* xb  = (short*)(ws + 0);         // 6,291,456
  short* BTn = (short*)(ws + 6291456);   // 1,572,864
  short* BT1 = (short*)(ws + 7864320);   // 12,582,912
  short* BT2 = (short*)(ws + 20447232);  // 12,681,216
  float* hn  = (float*)(ws + 33128448);  // 16,777,216
  float* wgt = (float*)(ws + 49905664);  // 1,048,576
  short* hs  = (short*)(ws + 50954240);  // 67,633,152
  float* p1  = (float*)(ws + 0);         // over xb+BTn+BT1 (dead during gemm2)
  float* p2  = (float*)(ws + 33128448);  // over hn (dead during gemm2)

  // 1. conversions + node GEMM (fused, independent blocks)
  cvt_misc_k<<<6336, 256, 0, stream>>>(x, nw1, lb2, xb, BTn, BT2);
  node_cvt_k<<<3584, 256, 0, stream>>>(xb, BTn, hn, lw1, lw2, BT1, BT2);

  // 2. gates
  gates_k<<<1024, 256, 0, stream>>>(hn, nb1, nw2, nb2, wgt, hs);

  // 3. GEMM1 (8-phase 256^2): hs = bf16(relu(xb @ BT1^T + b1) * w[leaf])
  gemm8p<<<512, 512, 0, stream>>>(xb, BT1, hs, 12, 768, 768, 8256, 32, lb1, wgt);

  // 4. GEMM2: out = hs @ BT2^T (4096x768, K=8256; b2 folded via K-ext), split-K=3
  gemm4<64, 5><<<1152, 256, 0, stream>>>(hs, BT2, (float*)d_out, p1, p2,
                                         129, 43, 8256, 8256, 768, 6, 64);
  // 5. out += p1 + p2
  reduce_k<<<3072, 256, 0, stream>>>((float*)d_out, p1, p2);
}

// Round 7
// 169.183 us; speedup vs baseline: 1.1666x; 1.0705x over previous
//
#include <hip/hip_runtime.h>
#include <stdint.h>
#include <stddef.h>

typedef __attribute__((ext_vector_type(8))) short short8;
typedef __attribute__((ext_vector_type(4))) float f32x4;
typedef __attribute__((ext_vector_type(4))) short short4v;

__device__ __forceinline__ short f2bf(float f) {
  unsigned u = __builtin_bit_cast(unsigned, f);
  u = (u + 0x7fffu + ((u >> 16) & 1u)) >> 16;
  return (short)u;
}

__device__ __forceinline__ void gload16(const void* g, void* l) {
  __builtin_amdgcn_global_load_lds(
      (const __attribute__((address_space(1))) unsigned int*)g,
      (__attribute__((address_space(3))) unsigned int*)l, 16, 0, 0);
}

// ---------------- conversion kernels ----------------

__global__ __launch_bounds__(256)
void cvt_misc_k(const float* __restrict__ x, const float* __restrict__ nw1,
                const float* __restrict__ lb2, short* __restrict__ xb,
                short* __restrict__ BTn, short* __restrict__ BT2) {
  const int bx = blockIdx.x;
  if (bx < 3072) {
    const int i = bx * 256 + threadIdx.x;
    const float4 v = ((const float4*)x)[i];
    short4v o;
    o.x = f2bf(v.x); o.y = f2bf(v.y); o.z = f2bf(v.z); o.w = f2bf(v.w);
    *(short4v*)(xb + (size_t)i * 4) = o;
  } else if (bx < 6144) {
    const int idx = (bx - 3072) * 256 + threadIdx.x;  // 1024*768
    const int i = idx % 768;
    const int nh = idx / 768;
    float v = 0.f;
    if (nh < 1008) v = nw1[((size_t)(nh >> 4) * 768 + i) * 16 + (nh & 15)];
    BTn[idx] = f2bf(v);
  } else {
    const int idx = (bx - 6144) * 256 + threadIdx.x;  // 768*64
    const int o = idx >> 6, l = idx & 63;
    BT2[(size_t)o * 8256 + 8192 + l] = f2bf(lb2[(size_t)l * 768 + o]);
  }
}

// Fused: blocks [0,512) = node GEMM hn = xb @ BTn^T (4096x1024, K=768, BM=64);
// blocks [512, 3584) = weight transposes (lw1->BT1, lw2->BT2).
__global__ __launch_bounds__(256, 4)
void node_cvt_k(const short* __restrict__ xb, const short* __restrict__ BTn,
                float* __restrict__ hn, const float* __restrict__ lw1,
                const float* __restrict__ lw2, short* __restrict__ BT1,
                short* __restrict__ BT2) {
  __shared__ char sh[24576];
  const int tid = threadIdx.x;
  if (blockIdx.x < 512) {
    constexpr int ABYTES = 64 * 128;
    const int lane = tid & 63, wid = tid >> 6;
    const int wm = wid >> 1, wn = wid & 1;
    const int sid = (blockIdx.x & 7) * 64 + (blockIdx.x >> 3);
    const int xg = sid % 8, yg = sid / 8;
    const int m0 = yg * 64, n0 = xg * 128;
    f32x4 acc[2][4];
    const f32x4 zero = {0.f, 0.f, 0.f, 0.f};
#pragma unroll
    for (int i = 0; i < 2; ++i)
#pragma unroll
      for (int j = 0; j < 4; ++j) acc[i][j] = zero;
    for (int ki = 0; ki < 12; ++ki) {
      const int k0 = ki * 64;
      __syncthreads();
#pragma unroll
      for (int s = 0; s < 6; ++s) {
        const int off = s * 4096 + tid * 16;
        const short* src;
        if (off < ABYTES) {
          const int r = off >> 7;
          const int cs = ((off >> 4) & 7) ^ (r & 7);
          src = xb + (size_t)(m0 + r) * 768 + k0 + cs * 8;
        } else {
          const int o2 = off - ABYTES;
          const int r = o2 >> 7;
          const int cs = ((o2 >> 4) & 7) ^ (r & 7);
          src = BTn + (size_t)(n0 + r) * 768 + k0 + cs * 8;
        }
        gload16(src, sh + off);
      }
      __syncthreads();
#pragma unroll
      for (int kk = 0; kk < 2; ++kk) {
        const int chunk = kk * 4 + (lane >> 4);
        short8 af[2], bfr[4];
#pragma unroll
        for (int i = 0; i < 2; ++i) {
          const int row = wm * 32 + i * 16 + (lane & 15);
          af[i] = *(const short8*)(sh + row * 128 + ((chunk ^ (row & 7)) << 4));
        }
#pragma unroll
        for (int j = 0; j < 4; ++j) {
          const int row = wn * 64 + j * 16 + (lane & 15);
          bfr[j] = *(const short8*)(sh + ABYTES + row * 128 + ((chunk ^ (row & 7)) << 4));
        }
#pragma unroll
        for (int i = 0; i < 2; ++i)
#pragma unroll
          for (int j = 0; j < 4; ++j)
            acc[i][j] = __builtin_amdgcn_mfma_f32_16x16x32_bf16(af[i], bfr[j], acc[i][j], 0, 0, 0);
      }
    }
    const int row_base = m0 + wm * 32 + (lane >> 4) * 4;
    const int col_base = n0 + wn * 64 + (lane & 15);
#pragma unroll
    for (int i = 0; i < 2; ++i)
#pragma unroll
      for (int j = 0; j < 4; ++j)
#pragma unroll
        for (int r = 0; r < 4; ++r)
          hn[(size_t)(row_base + i * 16 + r) * 1024 + col_base + j * 16] = acc[i][j][r];
  } else {
    float (*tile)[65] = (float(*)[65])sh;
    const int cb = blockIdx.x - 512;  // [0,3072)
    const int z = cb / 24, rem = cb % 24;
    const int by = rem / 12, bxx = rem % 12;
    const int h0 = by * 64, i0 = bxx * 64;
    if (z < 64) {
      const int l = z;
#pragma unroll
      for (int t = 0; t < 16; ++t) {
        const int e = t * 256 + tid;
        const int ii = e >> 6, hh = e & 63;
        tile[ii][hh] = lw1[(size_t)l * 98304 + (size_t)(i0 + ii) * 128 + (h0 + hh)];
      }
      __syncthreads();
#pragma unroll
      for (int t = 0; t < 16; ++t) {
        const int e = t * 256 + tid;
        const int hh = e >> 6, ii = e & 63;
        BT1[(size_t)(l * 128 + h0 + hh) * 768 + i0 + ii] = f2bf(tile[ii][hh]);
      }
    } else {
      const int l = z - 64;
      const int o0 = i0;
#pragma unroll
      for (int t = 0; t < 16; ++t) {
        const int e = t * 256 + tid;
        const int hh = e >> 6, oo = e & 63;
        tile[hh][oo] = lw2[(size_t)l * 98304 + (size_t)(h0 + hh) * 768 + (o0 + oo)];
      }
      __syncthreads();
#pragma unroll
      for (int t = 0; t < 16; ++t) {
        const int e = t * 256 + tid;
        const int oo = e >> 6, hh = e & 63;
        BT2[(size_t)(o0 + oo) * 8256 + l * 128 + h0 + hh] = f2bf(tile[hh][oo]);
      }
    }
  }
}

// ---------------- gate kernel ----------------
__global__ __launch_bounds__(256)
void gates_k(const float* __restrict__ hn, const float* __restrict__ nb1,
             const float* __restrict__ nw2, const float* __restrict__ nb2,
             float* __restrict__ wgt, short* __restrict__ hs) {
  const int b = blockIdx.x * 4 + (threadIdx.x >> 6);
  const int lane = threadIdx.x & 63;
  float c = 0.f;
  if (lane < 63) {
    float s = nb2[lane];
    const float* h = hn + (size_t)b * 1024 + lane * 16;
#pragma unroll
    for (int j = 0; j < 16; ++j) {
      float v = fmaxf(h[j] + nb1[lane * 16 + j], 0.f);
      s += v * nw2[lane * 16 + j];
    }
    c = 1.f / (1.f + expf(-s));
  }
  float w = 1.f;
#pragma unroll
  for (int lvl = 0; lvl < 6; ++lvl) {
    const int idx = (1 << lvl) - 1 + (lane >> (6 - lvl));
    const float g = __shfl(c, idx, 64);
    w *= ((lane >> (5 - lvl)) & 1) ? (1.f - g) : g;
  }
  wgt[(size_t)b * 64 + lane] = w;
  hs[(size_t)b * 8256 + 8192 + lane] = f2bf(w);
}

// ---------------- gemm8p: 256x256 8-phase GEMM1 (unchanged) ----------------
__global__ __launch_bounds__(512, 2)
void gemm8p(const short* __restrict__ A, const short* __restrict__ B,
            short* __restrict__ C, int KT, int lda, int ldb, int ldc,
            int nx, const float* __restrict__ bias, const float* __restrict__ wgt) {
  constexpr int ABYTES = 256 * 128;
  constexpr int TILEB = 2 * ABYTES;
  __shared__ char lds[2 * TILEB];

  const int tid = threadIdx.x, lane = tid & 63, wid = tid >> 6;
  const int wm = wid >> 2, wn = wid & 3;

  const int cpx = gridDim.x >> 3;
  const int sid = (blockIdx.x & 7) * cpx + (blockIdx.x >> 3);
  const int xg = sid % nx, yg = sid / nx;
  const int m0 = yg * 256, n0 = xg * 256;

  f32x4 acc[8][4];
  const f32x4 zero = {0.f, 0.f, 0.f, 0.f};
#pragma unroll
  for (int i = 0; i < 8; ++i)
#pragma unroll
    for (int j = 0; j < 4; ++j) acc[i][j] = zero;

  auto STG = [&](int buf, int mat, int h, int kt) {
    const int k0 = kt * 64;
    char* dst = lds + buf * TILEB + mat * ABYTES + h * 16384;
    const short* base = mat ? B : A;
    const int ld = mat ? ldb : lda;
    const int r0 = (mat ? n0 : m0) + h * 128;
#pragma unroll
    for (int s = 0; s < 2; ++s) {
      const int off = s * 8192 + tid * 16;
      const int r = off >> 7;
      const int cs = ((off >> 4) & 7) ^ (r & 7);
      gload16(base + (size_t)(r0 + r) * ld + k0 + cs * 8, dst + off);
    }
  };

  short8 bfrag[4][2];
  auto RD_B = [&](int buf) {
    const char* bB = lds + buf * TILEB + ABYTES;
#pragma unroll
    for (int j = 0; j < 4; ++j)
#pragma unroll
      for (int kk = 0; kk < 2; ++kk) {
        const int row = wn * 64 + j * 16 + (lane & 15);
        const int chunk = kk * 4 + (lane >> 4);
        bfrag[j][kk] = *(const short8*)(bB + row * 128 + ((chunk ^ (row & 7)) << 4));
      }
  };

  auto PH = [&](int buf, int q, bool rdB, int vm, auto&& stages) {
    if (rdB) RD_B(buf);
    const char* bA = lds + buf * TILEB;
    short8 af[2][2];
#pragma unroll
    for (int i = 0; i < 2; ++i)
#pragma unroll
      for (int kk = 0; kk < 2; ++kk) {
        const int row = wm * 128 + q * 32 + i * 16 + (lane & 15);
        const int chunk = kk * 4 + (lane >> 4);
        af[i][kk] = *(const short8*)(bA + row * 128 + ((chunk ^ (row & 7)) << 4));
      }
    stages();
    if (vm == 4) asm volatile("s_waitcnt vmcnt(4)" ::: "memory");
    else if (vm == 0) asm volatile("s_waitcnt vmcnt(0)" ::: "memory");
    __builtin_amdgcn_s_barrier();
    __builtin_amdgcn_s_setprio(1);
#pragma unroll
    for (int kk = 0; kk < 2; ++kk)
#pragma unroll
      for (int i = 0; i < 2; ++i)
#pragma unroll
        for (int j = 0; j < 4; ++j)
          acc[q * 2 + i][j] =
              __builtin_amdgcn_mfma_f32_16x16x32_bf16(af[i][kk], bfrag[j][kk], acc[q * 2 + i][j], 0, 0, 0);
    __builtin_amdgcn_s_setprio(0);
    __builtin_amdgcn_s_barrier();
  };

  STG(0, 0, 0, 0); STG(0, 0, 1, 0); STG(0, 1, 0, 0); STG(0, 1, 1, 0);
  STG(1, 1, 0, 1); STG(1, 1, 1, 1);
  asm volatile("s_waitcnt vmcnt(4)" ::: "memory");
  __builtin_amdgcn_s_barrier();

  const int iters = KT >> 1;
  for (int it = 0; it < iters; ++it) {
    const int t0 = it * 2;
    const bool last = (it == iters - 1);
    PH(0, 0, true, -1, [&] { if (t0 + 1 < KT) STG(1, 0, 0, t0 + 1); });
    PH(0, 1, false, -1, [&] {
      if (t0 + 1 < KT) STG(1, 0, 1, t0 + 1);
      if (t0 + 2 < KT) STG(0, 1, 0, t0 + 2);
    });
    PH(0, 2, false, -1, [&] { if (t0 + 2 < KT) STG(0, 1, 1, t0 + 2); });
    PH(0, 3, false, last ? 0 : 4, [] {});
    PH(1, 0, true, -1, [&] { if (t0 + 2 < KT) STG(0, 0, 0, t0 + 2); });
    PH(1, 1, false, -1, [&] { if (t0 + 2 < KT) STG(0, 0, 1, t0 + 2); });
    PH(1, 2, false, -1, [&] { if (t0 + 3 < KT) STG(1, 1, 0, t0 + 3); });
    PH(1, 3, false, last ? -1 : 4, [&] { if (t0 + 3 < KT) STG(1, 1, 1, t0 + 3); });
  }

#pragma unroll
  for (int mi = 0; mi < 8; ++mi) {
    const int row_base = m0 + wm * 128 + mi * 16 + (lane >> 4) * 4;
#pragma unroll
    for (int j = 0; j < 4; ++j) {
      const int col = n0 + wn * 64 + j * 16 + (lane & 15);
      const int leaf = col >> 7;
      const float b = bias[col];
#pragma unroll
      for (int r = 0; r < 4; ++r) {
        const int row = row_base + r;
        const float v = fmaxf(acc[mi][j][r] + b, 0.f) * wgt[(size_t)row * 64 + leaf];
        C[(size_t)row * ldc + col] = f2bf(v);
      }
    }
  }
}

// ---------------- gemm2k: BM=128 m97-structure, split-K=4, f32 partials ----------------
// z=0 -> out; z=1..3 -> P[z-1]. Grid 6*32*4 = 768 = 3 blocks/CU.
__global__ __launch_bounds__(256, 3)
void gemm2k(const short* __restrict__ A, const short* __restrict__ B,
            float* __restrict__ Out, float* __restrict__ P1,
            float* __restrict__ P2, float* __restrict__ P3,
            int KT, int ks, int lda, int ldb, int ldc, int nx, int ny) {
  constexpr int BM = 128;
  constexpr int ABYTES = BM * 128;
  constexpr int BBYTES = 128 * 128;
  constexpr int FM = BM / 32;
  constexpr int NLOAD = (ABYTES + BBYTES) / (256 * 16);
  __shared__ char lds[ABYTES + BBYTES];

  const int tid = threadIdx.x, lane = tid & 63, wid = tid >> 6;
  const int wm = wid >> 1, wn = wid & 1;

  const int cpx = gridDim.x >> 3;
  const int sid = (blockIdx.x & 7) * cpx + (blockIdx.x >> 3);
  const int xg = sid % nx;
  const int t1 = sid / nx;
  const int yg = t1 % ny;
  const int z = t1 / ny;
  const int m0 = yg * BM, n0 = xg * 128;
  const int kt0 = z * ks;
  const int ktn = min(ks, KT - kt0);

  f32x4 acc[FM][4];
  const f32x4 zero = {0.f, 0.f, 0.f, 0.f};
#pragma unroll
  for (int i = 0; i < FM; ++i)
#pragma unroll
    for (int j = 0; j < 4; ++j) acc[i][j] = zero;

  for (int ki = 0; ki < ktn; ++ki) {
    const int k0 = (kt0 + ki) * 64;
    __syncthreads();
#pragma unroll
    for (int s = 0; s < NLOAD; ++s) {
      const int off = s * 4096 + tid * 16;
      const short* src;
      if (off < ABYTES) {
        const int r = off >> 7;
        const int cs = ((off >> 4) & 7) ^ (r & 7);
        src = A + (size_t)(m0 + r) * lda + k0 + cs * 8;
      } else {
        const int o2 = off - ABYTES;
        const int r = o2 >> 7;
        const int cs = ((o2 >> 4) & 7) ^ (r & 7);
        src = B + (size_t)(n0 + r) * ldb + k0 + cs * 8;
      }
      gload16(src, lds + off);
    }
    __syncthreads();

    const char* ldsA = lds;
    const char* ldsB = lds + ABYTES;
#pragma unroll
    for (int kk = 0; kk < 2; ++kk) {
      const int chunk = kk * 4 + (lane >> 4);
      short8 af[FM], bfr[4];
#pragma unroll
      for (int i = 0; i < FM; ++i) {
        const int row = wm * (BM / 2) + i * 16 + (lane & 15);
        af[i] = *(const short8*)(ldsA + row * 128 + ((chunk ^ (row & 7)) << 4));
      }
#pragma unroll
      for (int j = 0; j < 4; ++j) {
        const int row = wn * 64 + j * 16 + (lane & 15);
        bfr[j] = *(const short8*)(ldsB + row * 128 + ((chunk ^ (row & 7)) << 4));
      }
      __builtin_amdgcn_s_setprio(1);
#pragma unroll
      for (int i = 0; i < FM; ++i)
#pragma unroll
        for (int j = 0; j < 4; ++j)
          acc[i][j] = __builtin_amdgcn_mfma_f32_16x16x32_bf16(af[i], bfr[j], acc[i][j], 0, 0, 0);
      __builtin_amdgcn_s_setprio(0);
    }
  }

  const int row_base = m0 + wm * (BM / 2) + (lane >> 4) * 4;
  const int col_base = n0 + wn * 64 + (lane & 15);
  float* C = (z == 0) ? Out : (z == 1 ? P1 : (z == 2 ? P2 : P3));
#pragma unroll
  for (int i = 0; i < FM; ++i)
#pragma unroll
    for (int j = 0; j < 4; ++j) {
      const int col = col_base + j * 16;
#pragma unroll
      for (int r = 0; r < 4; ++r) {
        const int row = row_base + i * 16 + r;
        C[(size_t)row * ldc + col] = acc[i][j][r];
      }
    }
}

// ---------------- split-K reduce: out += p1 + p2 + p3 ----------------
__global__ __launch_bounds__(256)
void reduce_k(float* __restrict__ out, const float* __restrict__ p1,
              const float* __restrict__ p2, const float* __restrict__ p3) {
  const int i = blockIdx.x * 256 + threadIdx.x;  // 786432 threads, f32x4 each
  f32x4 a = ((const f32x4*)out)[i];
  f32x4 b = ((const f32x4*)p1)[i];
  f32x4 c = ((const f32x4*)p2)[i];
  f32x4 d = ((const f32x4*)p3)[i];
  ((f32x4*)out)[i] = (a + b) + (c + d);
}

// ---------------- launch ----------------

extern "C" void kernel_launch(void* const* d_in, const int* in_sizes, int n_in,
                              void* d_out, int out_size, void* d_ws, size_t ws_size,
                              hipStream_t stream) {
  const float* x   = (const float*)d_in[0];
  const float* nw1 = (const float*)d_in[1];
  const float* nb1 = (const float*)d_in[2];
  const float* nw2 = (const float*)d_in[3];
  const float* nb2 = (const float*)d_in[4];
  const float* lw1 = (const float*)d_in[5];
  const float* lb1 = (const float*)d_in[6];
  const float* lw2 = (const float*)d_in[7];
  const float* lb2 = (const float*)d_in[8];

  char* ws = (char*)d_ws;
  // Layout: gemm2k-dead buffers first (contiguous 38.27 MB), then live ones.
  short* xb  = (short*)(ws + 0);         // 6,291,456   (dead after gemm8p)
  short* BT1 = (short*)(ws + 6291456);   // 12,582,912  (dead after gemm8p)
  short* BTn = (short*)(ws + 18874368);  // 1,572,864   (dead after node_cvt)
  float* hn  = (float*)(ws + 20447232);  // 16,777,216  (dead after gates)
  float* wgt = (float*)(ws + 37224448);  // 1,048,576   (dead after gemm8p)
  short* BT2 = (short*)(ws + 38273024);  // 12,681,216  (live in gemm2k)
  short* hs  = (short*)(ws + 50954240);  // 67,633,152  (live in gemm2k)
  // f32 split-K partials over the dead [0, 38.27 MB) region during gemm2k:
  float* p1  = (float*)(ws + 0);         // 12,582,912
  float* p2  = (float*)(ws + 12582912);  // 12,582,912
  float* p3  = (float*)(ws + 25165824);  // 12,582,912 (ends 37,748,736 < 38,273,024)

  // 1. conversions + node GEMM (fused, independent blocks)
  cvt_misc_k<<<6336, 256, 0, stream>>>(x, nw1, lb2, xb, BTn, BT2);
  node_cvt_k<<<3584, 256, 0, stream>>>(xb, BTn, hn, lw1, lw2, BT1, BT2);

  // 2. gates
  gates_k<<<1024, 256, 0, stream>>>(hn, nb1, nw2, nb2, wgt, hs);

  // 3. GEMM1 (8-phase 256^2): hs = bf16(relu(xb @ BT1^T + b1) * w[leaf])
  gemm8p<<<512, 512, 0, stream>>>(xb, BT1, hs, 12, 768, 768, 8256, 32, lb1, wgt);

  // 4. GEMM2: out = hs @ BT2^T (4096x768, K=8256; b2 folded via K-ext),
  //    BM=128, split-K=4 (ks=33,33,33,30), grid 768 = 3 blocks/CU
  gemm2k<<<768, 256, 0, stream>>>(hs, BT2, (float*)d_out, p1, p2, p3,
                                  129, 33, 8256, 8256, 768, 6, 32);
  // 5. out += p1 + p2 + p3   (3,145,728 f32 = 786,432 threads)
  reduce_k<<<3072, 256, 0, stream>>>((float*)d_out, p1, p2, p3);
}

// Round 8
// 161.136 us; speedup vs baseline: 1.2248x; 1.0499x over previous
//
#include <hip/hip_runtime.h>
#include <stdint.h>
#include <stddef.h>

typedef __attribute__((ext_vector_type(8))) short short8;
typedef __attribute__((ext_vector_type(4))) float f32x4;
typedef __attribute__((ext_vector_type(4))) short short4v;

__device__ __forceinline__ short f2bf(float f) {
  unsigned u = __builtin_bit_cast(unsigned, f);
  u = (u + 0x7fffu + ((u >> 16) & 1u)) >> 16;
  return (short)u;
}

__device__ __forceinline__ void gload16(const void* g, void* l) {
  __builtin_amdgcn_global_load_lds(
      (const __attribute__((address_space(1))) unsigned int*)g,
      (__attribute__((address_space(3))) unsigned int*)l, 16, 0, 0);
}

// ---------------- conversion kernels ----------------

__global__ __launch_bounds__(256)
void cvt_misc_k(const float* __restrict__ x, const float* __restrict__ nw1,
                const float* __restrict__ lb2, short* __restrict__ xb,
                short* __restrict__ BTn, short* __restrict__ BT2) {
  const int bx = blockIdx.x;
  if (bx < 3072) {
    const int i = bx * 256 + threadIdx.x;
    const float4 v = ((const float4*)x)[i];
    short4v o;
    o.x = f2bf(v.x); o.y = f2bf(v.y); o.z = f2bf(v.z); o.w = f2bf(v.w);
    *(short4v*)(xb + (size_t)i * 4) = o;
  } else if (bx < 6144) {
    const int idx = (bx - 3072) * 256 + threadIdx.x;  // 1024*768
    const int i = idx % 768;
    const int nh = idx / 768;
    float v = 0.f;
    if (nh < 1008) v = nw1[((size_t)(nh >> 4) * 768 + i) * 16 + (nh & 15)];
    BTn[idx] = f2bf(v);
  } else {
    const int idx = (bx - 6144) * 256 + threadIdx.x;  // 768*64
    const int o = idx >> 6, l = idx & 63;
    BT2[(size_t)o * 8256 + 8192 + l] = f2bf(lb2[(size_t)l * 768 + o]);
  }
}

// Fused: blocks [0,512) = node GEMM hn = xb @ BTn^T (4096x1024, K=768, BM=64);
// blocks [512, 3584) = weight transposes (lw1->BT1, lw2->BT2).
__global__ __launch_bounds__(256, 4)
void node_cvt_k(const short* __restrict__ xb, const short* __restrict__ BTn,
                float* __restrict__ hn, const float* __restrict__ lw1,
                const float* __restrict__ lw2, short* __restrict__ BT1,
                short* __restrict__ BT2) {
  __shared__ char sh[24576];
  const int tid = threadIdx.x;
  if (blockIdx.x < 512) {
    constexpr int ABYTES = 64 * 128;
    const int lane = tid & 63, wid = tid >> 6;
    const int wm = wid >> 1, wn = wid & 1;
    const int sid = (blockIdx.x & 7) * 64 + (blockIdx.x >> 3);
    const int xg = sid % 8, yg = sid / 8;
    const int m0 = yg * 64, n0 = xg * 128;
    f32x4 acc[2][4];
    const f32x4 zero = {0.f, 0.f, 0.f, 0.f};
#pragma unroll
    for (int i = 0; i < 2; ++i)
#pragma unroll
      for (int j = 0; j < 4; ++j) acc[i][j] = zero;
    for (int ki = 0; ki < 12; ++ki) {
      const int k0 = ki * 64;
      __syncthreads();
#pragma unroll
      for (int s = 0; s < 6; ++s) {
        const int off = s * 4096 + tid * 16;
        const short* src;
        if (off < ABYTES) {
          const int r = off >> 7;
          const int cs = ((off >> 4) & 7) ^ (r & 7);
          src = xb + (size_t)(m0 + r) * 768 + k0 + cs * 8;
        } else {
          const int o2 = off - ABYTES;
          const int r = o2 >> 7;
          const int cs = ((o2 >> 4) & 7) ^ (r & 7);
          src = BTn + (size_t)(n0 + r) * 768 + k0 + cs * 8;
        }
        gload16(src, sh + off);
      }
      __syncthreads();
#pragma unroll
      for (int kk = 0; kk < 2; ++kk) {
        const int chunk = kk * 4 + (lane >> 4);
        short8 af[2], bfr[4];
#pragma unroll
        for (int i = 0; i < 2; ++i) {
          const int row = wm * 32 + i * 16 + (lane & 15);
          af[i] = *(const short8*)(sh + row * 128 + ((chunk ^ (row & 7)) << 4));
        }
#pragma unroll
        for (int j = 0; j < 4; ++j) {
          const int row = wn * 64 + j * 16 + (lane & 15);
          bfr[j] = *(const short8*)(sh + ABYTES + row * 128 + ((chunk ^ (row & 7)) << 4));
        }
#pragma unroll
        for (int i = 0; i < 2; ++i)
#pragma unroll
          for (int j = 0; j < 4; ++j)
            acc[i][j] = __builtin_amdgcn_mfma_f32_16x16x32_bf16(af[i], bfr[j], acc[i][j], 0, 0, 0);
      }
    }
    const int row_base = m0 + wm * 32 + (lane >> 4) * 4;
    const int col_base = n0 + wn * 64 + (lane & 15);
#pragma unroll
    for (int i = 0; i < 2; ++i)
#pragma unroll
      for (int j = 0; j < 4; ++j)
#pragma unroll
        for (int r = 0; r < 4; ++r)
          hn[(size_t)(row_base + i * 16 + r) * 1024 + col_base + j * 16] = acc[i][j][r];
  } else {
    float (*tile)[65] = (float(*)[65])sh;
    const int cb = blockIdx.x - 512;  // [0,3072)
    const int z = cb / 24, rem = cb % 24;
    const int by = rem / 12, bxx = rem % 12;
    const int h0 = by * 64, i0 = bxx * 64;
    if (z < 64) {
      const int l = z;
#pragma unroll
      for (int t = 0; t < 16; ++t) {
        const int e = t * 256 + tid;
        const int ii = e >> 6, hh = e & 63;
        tile[ii][hh] = lw1[(size_t)l * 98304 + (size_t)(i0 + ii) * 128 + (h0 + hh)];
      }
      __syncthreads();
#pragma unroll
      for (int t = 0; t < 16; ++t) {
        const int e = t * 256 + tid;
        const int hh = e >> 6, ii = e & 63;
        BT1[(size_t)(l * 128 + h0 + hh) * 768 + i0 + ii] = f2bf(tile[ii][hh]);
      }
    } else {
      const int l = z - 64;
      const int o0 = i0;
#pragma unroll
      for (int t = 0; t < 16; ++t) {
        const int e = t * 256 + tid;
        const int hh = e >> 6, oo = e & 63;
        tile[hh][oo] = lw2[(size_t)l * 98304 + (size_t)(h0 + hh) * 768 + (o0 + oo)];
      }
      __syncthreads();
#pragma unroll
      for (int t = 0; t < 16; ++t) {
        const int e = t * 256 + tid;
        const int oo = e >> 6, hh = e & 63;
        BT2[(size_t)(o0 + oo) * 8256 + l * 128 + h0 + hh] = f2bf(tile[hh][oo]);
      }
    }
  }
}

// ---------------- gate kernel ----------------
__global__ __launch_bounds__(256)
void gates_k(const float* __restrict__ hn, const float* __restrict__ nb1,
             const float* __restrict__ nw2, const float* __restrict__ nb2,
             float* __restrict__ wgt, short* __restrict__ hs) {
  const int b = blockIdx.x * 4 + (threadIdx.x >> 6);
  const int lane = threadIdx.x & 63;
  float c = 0.f;
  if (lane < 63) {
    float s = nb2[lane];
    const float* h = hn + (size_t)b * 1024 + lane * 16;
#pragma unroll
    for (int j = 0; j < 16; ++j) {
      float v = fmaxf(h[j] + nb1[lane * 16 + j], 0.f);
      s += v * nw2[lane * 16 + j];
    }
    c = 1.f / (1.f + expf(-s));
  }
  float w = 1.f;
#pragma unroll
  for (int lvl = 0; lvl < 6; ++lvl) {
    const int idx = (1 << lvl) - 1 + (lane >> (6 - lvl));
    const float g = __shfl(c, idx, 64);
    w *= ((lane >> (5 - lvl)) & 1) ? (1.f - g) : g;
  }
  wgt[(size_t)b * 64 + lane] = w;
  hs[(size_t)b * 8256 + 8192 + lane] = f2bf(w);
}

// ---------------- gemm8x: 256x256 8-phase GEMM (both GEMM1 and GEMM2) ----------------
// EPI1 (GEMM1): A=xb(768), B=BT1(768), C bf16 = relu(acc+bias)*wgt, ldc 8256,
//   grid 512 = 32xg x 16yg, 2D XCD chunk (4x2 chunks of 8x8), KT=12.
// EPI0 (GEMM2): A=hs(8256), B=BT2(8256), C f32 -> {Out,P1,P2,P3}[z], ldc 768,
//   grid 192 = 3xg x 16yg x 4z, splits {32,32,32,33} (z=3 odd -> single-tile tail).
// Stage ledger identical to verified R5 gemm8p; tail: vmcnt(0)+barrier, 4 quad
// phases, no staging (nothing outstanding afterward).
template <int EPI>
__global__ __launch_bounds__(512, 2)
void gemm8x(const short* __restrict__ A, const short* __restrict__ B,
            void* __restrict__ C0, float* __restrict__ P1, float* __restrict__ P2,
            float* __restrict__ P3, const float* __restrict__ bias,
            const float* __restrict__ wgt) {
  constexpr int LDA = EPI ? 768 : 8256;
  constexpr int LDB = EPI ? 768 : 8256;
  constexpr int LDC = EPI ? 8256 : 768;
  constexpr int ABYTES = 256 * 128;
  constexpr int TILEB = 2 * ABYTES;
  __shared__ char lds[2 * TILEB];

  const int tid = threadIdx.x, lane = tid & 63, wid = tid >> 6;
  const int wm = wid >> 2, wn = wid & 3;

  const int c = blockIdx.x & 7, ii = blockIdx.x >> 3;
  int xg, yg, kt0, ktn, zz;
  if constexpr (EPI == 1) {
    xg = ((c & 3) << 3) + (ii & 7);   // [0,32)
    yg = ((c >> 2) << 3) + (ii >> 3); // [0,16)
    kt0 = 0; ktn = 12; zz = 0;
  } else {
    xg = ii % 3;                      // [0,3)
    const int yz = c * 8 + ii / 3;    // [0,64)
    yg = yz & 15;
    zz = yz >> 4;                     // [0,4)
    kt0 = zz * 32;
    ktn = (zz == 3) ? 33 : 32;
  }
  const int m0 = yg * 256, n0 = xg * 256;

  f32x4 acc[8][4];
  const f32x4 zero = {0.f, 0.f, 0.f, 0.f};
#pragma unroll
  for (int i = 0; i < 8; ++i)
#pragma unroll
    for (int j = 0; j < 4; ++j) acc[i][j] = zero;

  auto STG = [&](int buf, int mat, int h, int kt) {
    const int k0 = kt * 64;
    char* dst = lds + buf * TILEB + mat * ABYTES + h * 16384;
    const short* base = mat ? B : A;
    const int ld = mat ? LDB : LDA;
    const int r0 = (mat ? n0 : m0) + h * 128;
#pragma unroll
    for (int s = 0; s < 2; ++s) {
      const int off = s * 8192 + tid * 16;
      const int r = off >> 7;
      const int cs = ((off >> 4) & 7) ^ (r & 7);
      gload16(base + (size_t)(r0 + r) * ld + k0 + cs * 8, dst + off);
    }
  };

  short8 bfrag[4][2];
  auto RD_B = [&](int buf) {
    const char* bB = lds + buf * TILEB + ABYTES;
#pragma unroll
    for (int j = 0; j < 4; ++j)
#pragma unroll
      for (int kk = 0; kk < 2; ++kk) {
        const int row = wn * 64 + j * 16 + (lane & 15);
        const int chunk = kk * 4 + (lane >> 4);
        bfrag[j][kk] = *(const short8*)(bB + row * 128 + ((chunk ^ (row & 7)) << 4));
      }
  };

  auto PH = [&](int buf, int q, bool rdB, int vm, auto&& stages) {
    if (rdB) RD_B(buf);
    const char* bA = lds + buf * TILEB;
    short8 af[2][2];
#pragma unroll
    for (int i = 0; i < 2; ++i)
#pragma unroll
      for (int kk = 0; kk < 2; ++kk) {
        const int row = wm * 128 + q * 32 + i * 16 + (lane & 15);
        const int chunk = kk * 4 + (lane >> 4);
        af[i][kk] = *(const short8*)(bA + row * 128 + ((chunk ^ (row & 7)) << 4));
      }
    stages();
    if (vm == 4) asm volatile("s_waitcnt vmcnt(4)" ::: "memory");
    else if (vm == 0) asm volatile("s_waitcnt vmcnt(0)" ::: "memory");
    __builtin_amdgcn_s_barrier();
    __builtin_amdgcn_s_setprio(1);
#pragma unroll
    for (int kk = 0; kk < 2; ++kk)
#pragma unroll
      for (int i = 0; i < 2; ++i)
#pragma unroll
        for (int j = 0; j < 4; ++j)
          acc[q * 2 + i][j] =
              __builtin_amdgcn_mfma_f32_16x16x32_bf16(af[i][kk], bfrag[j][kk], acc[q * 2 + i][j], 0, 0, 0);
    __builtin_amdgcn_s_setprio(0);
    __builtin_amdgcn_s_barrier();
  };

  // prologue: tile kt0 (8 loads) + B(kt0+1) (4 loads); wait tile0
  STG(0, 0, 0, kt0); STG(0, 0, 1, kt0); STG(0, 1, 0, kt0); STG(0, 1, 1, kt0);
  STG(1, 1, 0, kt0 + 1); STG(1, 1, 1, kt0 + 1);
  asm volatile("s_waitcnt vmcnt(4)" ::: "memory");
  __builtin_amdgcn_s_barrier();

  const int iters = ktn >> 1;
  for (int it = 0; it < iters; ++it) {
    const int t0 = it * 2;
    const bool lastp = (it == iters - 1) && !(ktn & 1);
    const bool t2 = t0 + 2 < ktn, t3 = t0 + 3 < ktn;
    PH(0, 0, true, -1, [&] { STG(1, 0, 0, kt0 + t0 + 1); });
    PH(0, 1, false, -1, [&] {
      STG(1, 0, 1, kt0 + t0 + 1);
      if (t2) STG(0, 1, 0, kt0 + t0 + 2);
    });
    PH(0, 2, false, -1, [&] { if (t2) STG(0, 1, 1, kt0 + t0 + 2); });
    PH(0, 3, false, lastp ? 0 : 4, [] {});
    PH(1, 0, true, -1, [&] { if (t2) STG(0, 0, 0, kt0 + t0 + 2); });
    PH(1, 1, false, -1, [&] { if (t2) STG(0, 0, 1, kt0 + t0 + 2); });
    PH(1, 2, false, -1, [&] { if (t3) STG(1, 1, 0, kt0 + t0 + 3); });
    PH(1, 3, false, lastp ? -1 : 4, [&] { if (t3) STG(1, 1, 1, kt0 + t0 + 3); });
  }
  if (ktn & 1) {  // tail tile (ktn-1) fully staged into buf0; nothing else in flight
    asm volatile("s_waitcnt vmcnt(0)" ::: "memory");
    __builtin_amdgcn_s_barrier();
    RD_B(0);
    const char* bA = lds;
#pragma unroll
    for (int q = 0; q < 4; ++q) {
      short8 af[2][2];
#pragma unroll
      for (int i = 0; i < 2; ++i)
#pragma unroll
        for (int kk = 0; kk < 2; ++kk) {
          const int row = wm * 128 + q * 32 + i * 16 + (lane & 15);
          const int chunk = kk * 4 + (lane >> 4);
          af[i][kk] = *(const short8*)(bA + row * 128 + ((chunk ^ (row & 7)) << 4));
        }
      __builtin_amdgcn_s_setprio(1);
#pragma unroll
      for (int kk = 0; kk < 2; ++kk)
#pragma unroll
        for (int i = 0; i < 2; ++i)
#pragma unroll
          for (int j = 0; j < 4; ++j)
            acc[q * 2 + i][j] =
                __builtin_amdgcn_mfma_f32_16x16x32_bf16(af[i][kk], bfrag[j][kk], acc[q * 2 + i][j], 0, 0, 0);
      __builtin_amdgcn_s_setprio(0);
    }
  }

  if constexpr (EPI == 1) {
    short* C = (short*)C0;
#pragma unroll
    for (int mi = 0; mi < 8; ++mi) {
      const int row_base = m0 + wm * 128 + mi * 16 + (lane >> 4) * 4;
#pragma unroll
      for (int j = 0; j < 4; ++j) {
        const int col = n0 + wn * 64 + j * 16 + (lane & 15);
        const int leaf = col >> 7;
        const float b = bias[col];
#pragma unroll
        for (int r = 0; r < 4; ++r) {
          const int row = row_base + r;
          const float v = fmaxf(acc[mi][j][r] + b, 0.f) * wgt[(size_t)row * 64 + leaf];
          C[(size_t)row * LDC + col] = f2bf(v);
        }
      }
    }
  } else {
    float* C = (zz == 0) ? (float*)C0 : (zz == 1 ? P1 : (zz == 2 ? P2 : P3));
#pragma unroll
    for (int mi = 0; mi < 8; ++mi) {
      const int row_base = m0 + wm * 128 + mi * 16 + (lane >> 4) * 4;
#pragma unroll
      for (int j = 0; j < 4; ++j) {
        const int col = n0 + wn * 64 + j * 16 + (lane & 15);
#pragma unroll
        for (int r = 0; r < 4; ++r) {
          const int row = row_base + r;
          C[(size_t)row * LDC + col] = acc[mi][j][r];
        }
      }
    }
  }
}

// ---------------- split-K reduce: out += p1 + p2 + p3 ----------------
__global__ __launch_bounds__(256)
void reduce_k(float* __restrict__ out, const float* __restrict__ p1,
              const float* __restrict__ p2, const float* __restrict__ p3) {
  const int i = blockIdx.x * 256 + threadIdx.x;  // 786432 threads, f32x4 each
  f32x4 a = ((const f32x4*)out)[i];
  f32x4 b = ((const f32x4*)p1)[i];
  f32x4 c = ((const f32x4*)p2)[i];
  f32x4 d = ((const f32x4*)p3)[i];
  ((f32x4*)out)[i] = (a + b) + (c + d);
}

// ---------------- launch ----------------

extern "C" void kernel_launch(void* const* d_in, const int* in_sizes, int n_in,
                              void* d_out, int out_size, void* d_ws, size_t ws_size,
                              hipStream_t stream) {
  const float* x   = (const float*)d_in[0];
  const float* nw1 = (const float*)d_in[1];
  const float* nb1 = (const float*)d_in[2];
  const float* nw2 = (const float*)d_in[3];
  const float* nb2 = (const float*)d_in[4];
  const float* lw1 = (const float*)d_in[5];
  const float* lb1 = (const float*)d_in[6];
  const float* lw2 = (const float*)d_in[7];
  const float* lb2 = (const float*)d_in[8];

  char* ws = (char*)d_ws;
  // Layout (identical to proven R7): gemm2-dead buffers first, then live ones.
  short* xb  = (short*)(ws + 0);         // 6,291,456   (dead after gemm1)
  short* BT1 = (short*)(ws + 6291456);   // 12,582,912  (dead after gemm1)
  short* BTn = (short*)(ws + 18874368);  // 1,572,864   (dead after node_cvt)
  float* hn  = (float*)(ws + 20447232);  // 16,777,216  (dead after gates)
  float* wgt = (float*)(ws + 37224448);  // 1,048,576   (dead after gemm1)
  short* BT2 = (short*)(ws + 38273024);  // 12,681,216  (live in gemm2)
  short* hs  = (short*)(ws + 50954240);  // 67,633,152  (live in gemm2)
  // f32 split-K partials over the dead [0, 38.27 MB) region during gemm2:
  float* p1  = (float*)(ws + 0);         // 12,582,912
  float* p2  = (float*)(ws + 12582912);  // 12,582,912
  float* p3  = (float*)(ws + 25165824);  // 12,582,912 (ends 37,748,736)

  // 1. conversions + node GEMM (fused, independent blocks)
  cvt_misc_k<<<6336, 256, 0, stream>>>(x, nw1, lb2, xb, BTn, BT2);
  node_cvt_k<<<3584, 256, 0, stream>>>(xb, BTn, hn, lw1, lw2, BT1, BT2);

  // 2. gates
  gates_k<<<1024, 256, 0, stream>>>(hn, nb1, nw2, nb2, wgt, hs);

  // 3. GEMM1 (8-phase 256^2, 2D-chunk swizzle): hs = bf16(relu(xb@BT1^T+b1)*w)
  gemm8x<1><<<512, 512, 0, stream>>>(xb, BT1, hs, nullptr, nullptr, nullptr,
                                     lb1, wgt);

  // 4. GEMM2 (8-phase 256^2, split-K=4): out = hs @ BT2^T (K=8256, b2 folded)
  gemm8x<0><<<192, 512, 0, stream>>>(hs, BT2, d_out, p1, p2, p3,
                                     nullptr, nullptr);

  // 5. out += p1 + p2 + p3
  reduce_k<<<3072, 256, 0, stream>>>((float*)d_out, p1, p2, p3);
}